// Round 6
// baseline (42.600 us; speedup 1.0000x reference)
//
#include <hip/hip_runtime.h>

// out(p) = (49 - g·G)/8,  g = x/max(||x||_C,1e-8)  (g·g == 1 exactly in ref),
// G = 7x7 zero-padded box-sum of g (separable 7-tap H then V).
// LDS: g, h as packed-bf16 pairs. V-pass = register running sums (each h read once).

typedef unsigned int u32;
typedef float f32x2 __attribute__((ext_vector_type(2)));
typedef float f32x4 __attribute__((ext_vector_type(4)));

#define EPS2 1e-16f   // 1/max(sqrt(n2),1e-8) == rsq(max(n2,1e-16))

constexpr int TW  = 64;   // out tile width
constexpr int TH  = 32;   // out tile height
constexpr int RIN = 38;   // staged rows (TH+6)
constexpr int GS  = 36;   // g row stride, u32 (72 bf16 cols: img x0-4 .. x0+67)
constexpr int HS  = 34;   // h row stride, u32 (64 bf16 cols + pad)

__device__ __forceinline__ u32 packbf2(float a, float b) {
    // round-half-up bf16 pack (a=lo, b=hi); values bounded, no inf/nan
    const u32 ua = __float_as_uint(a), ub = __float_as_uint(b);
    return ((ua + 0x8000u) >> 16) | ((ub + 0x8000u) & 0xffff0000u);
}
__device__ __forceinline__ float uplo(u32 u) { return __uint_as_float(u << 16); }
__device__ __forceinline__ float uphi(u32 u) { return __uint_as_float(u & 0xffff0000u); }

__global__ __launch_bounds__(256, 5) void mcnd_kernel(const float* __restrict__ x,
                                                      float* __restrict__ out,
                                                      int B, int H, int W) {
    __shared__ __align__(16) u32 gsh[3][RIN][GS];   // 16,416 B
    __shared__ __align__(16) u32 hsh[3][RIN][HS];   // 15,504 B  (total 31,920)

    const int HW = H * W;
    const int tilesX = W / TW;                      // 8
    const int tilesPerImg = tilesX * (H / TH);      // 128

    // bijective XCD swizzle (grid 4096 % 8 == 0): contiguous tile runs per XCD
    const int cpx = gridDim.x >> 3;
    const int wg  = (blockIdx.x & 7) * cpx + (blockIdx.x >> 3);
    const int b   = wg / tilesPerImg;
    const int t   = wg % tilesPerImg;
    const int ty  = t / tilesX;
    const int tx  = t - ty * tilesX;
    const int y0  = ty * TH;
    const int x0  = tx * TW;

    const float* __restrict__ xb = x + (size_t)b * 3 * HW;
    const int tid = threadIdx.x;

    // ---- phase A: load + normalize -> packed-bf16 g ----
    for (int p = tid; p < RIN * 9; p += 256) {
        const int r = p / 9;
        const int k = p - 9 * r;
        const int gy = y0 + r - 3;
        const int gx = x0 + 8 * k - 4;              // 16B-aligned f32 col base
        f32x4 a0 = {0.f,0.f,0.f,0.f}, a1 = a0, b0 = a0, b1 = a0, c0 = a0, c1 = a0;
        if (gy >= 0 && gy < H) {
            const float* base = xb + (size_t)gy * W + gx;
            if (gx >= 0) {                          // left 4-col chunk wholly in/out
                a0 = *(const f32x4*)(base);
                b0 = *(const f32x4*)(base + HW);
                c0 = *(const f32x4*)(base + 2 * HW);
            }
            if (gx + 8 <= W) {                      // right 4-col chunk
                a1 = *(const f32x4*)(base + 4);
                b1 = *(const f32x4*)(base + HW + 4);
                c1 = *(const f32x4*)(base + 2 * HW + 4);
            }
        }
        float ga[8], gb[8], gc[8];
#pragma unroll
        for (int e = 0; e < 4; ++e) {
            {
                const float n2  = a0[e]*a0[e] + b0[e]*b0[e] + c0[e]*c0[e];
                const float inv = __builtin_amdgcn_rsqf(fmaxf(n2, EPS2));
                ga[e] = a0[e]*inv; gb[e] = b0[e]*inv; gc[e] = c0[e]*inv;
            }
            {
                const float n2  = a1[e]*a1[e] + b1[e]*b1[e] + c1[e]*c1[e];
                const float inv = __builtin_amdgcn_rsqf(fmaxf(n2, EPS2));
                ga[e+4] = a1[e]*inv; gb[e+4] = b1[e]*inv; gc[e+4] = c1[e]*inv;
            }
        }
        uint4 wa, wb, wc;
        wa.x = packbf2(ga[0],ga[1]); wa.y = packbf2(ga[2],ga[3]);
        wa.z = packbf2(ga[4],ga[5]); wa.w = packbf2(ga[6],ga[7]);
        wb.x = packbf2(gb[0],gb[1]); wb.y = packbf2(gb[2],gb[3]);
        wb.z = packbf2(gb[4],gb[5]); wb.w = packbf2(gb[6],gb[7]);
        wc.x = packbf2(gc[0],gc[1]); wc.y = packbf2(gc[2],gc[3]);
        wc.z = packbf2(gc[4],gc[5]); wc.w = packbf2(gc[6],gc[7]);
        *(uint4*)&gsh[0][r][4*k] = wa;
        *(uint4*)&gsh[1][r][4*k] = wb;
        *(uint4*)&gsh[2][r][4*k] = wc;
    }
    __syncthreads();

    // ---- phase B: horizontal 7-tap, 8 out cols per work item (304 items) ----
    for (int p = tid; p < RIN * 8; p += 256) {
        const int r   = p >> 3;
        const int grp = p & 7;                      // out cols 8grp..8grp+7
#pragma unroll
        for (int ch = 0; ch < 3; ++ch) {
            const uint4 A0 = *(const uint4*)&gsh[ch][r][4*grp];
            const uint4 A1 = *(const uint4*)&gsh[ch][r][4*grp + 4];
            float c[16];
            c[0]=uplo(A0.x);  c[1]=uphi(A0.x);  c[2]=uplo(A0.y);  c[3]=uphi(A0.y);
            c[4]=uplo(A0.z);  c[5]=uphi(A0.z);  c[6]=uplo(A0.w);  c[7]=uphi(A0.w);
            c[8]=uplo(A1.x);  c[9]=uphi(A1.x);  c[10]=uplo(A1.y); c[11]=uphi(A1.y);
            c[12]=uplo(A1.z); c[13]=uphi(A1.z); c[14]=uplo(A1.w); c[15]=uphi(A1.w);
            // h col 8grp+m needs staged g cols 8grp+m+1 .. 8grp+m+7 -> c[m+1..m+7]
            float hp[8];
            hp[0] = c[1]+c[2]+c[3]+c[4]+c[5]+c[6]+c[7];
#pragma unroll
            for (int m = 1; m < 8; ++m) hp[m] = hp[m-1] - c[m] + c[m+7];
            uint2 w0, w1;
            w0.x = packbf2(hp[0], hp[1]); w0.y = packbf2(hp[2], hp[3]);
            w1.x = packbf2(hp[4], hp[5]); w1.y = packbf2(hp[6], hp[7]);
            *(uint2*)&hsh[ch][r][4*grp]     = w0;
            *(uint2*)&hsh[ch][r][4*grp + 2] = w1;
        }
    }
    __syncthreads();

    // ---- phase C: vertical 7-tap via register running sums ----
    // thread = (cp: 2 out cols) x (rb: 4 out rows); each h read exactly once
    {
        const int cp = tid & 31;                    // out cols 2cp, 2cp+1
        const int rb = tid >> 5;                    // out rows 4rb .. 4rb+3
        float Dlo[4] = {0.f,0.f,0.f,0.f}, Dhi[4] = {0.f,0.f,0.f,0.f};
#pragma unroll
        for (int ch = 0; ch < 3; ++ch) {
            u32 hv[10];
#pragma unroll
            for (int d = 0; d < 10; ++d) hv[d] = hsh[ch][4*rb + d][cp];
            float lo[10], hi[10];
#pragma unroll
            for (int d = 0; d < 10; ++d) { lo[d] = uplo(hv[d]); hi[d] = uphi(hv[d]); }
            u32 gv[4];
#pragma unroll
            for (int i = 0; i < 4; ++i) gv[i] = gsh[ch][4*rb + i + 3][cp + 2];
            float sl = lo[0]+lo[1]+lo[2]+lo[3]+lo[4]+lo[5]+lo[6];
            float sh = hi[0]+hi[1]+hi[2]+hi[3]+hi[4]+hi[5]+hi[6];
#pragma unroll
            for (int i = 0; i < 4; ++i) {
                Dlo[i] += uplo(gv[i]) * sl;
                Dhi[i] += uphi(gv[i]) * sh;
                if (i < 3) { sl += lo[i+7] - lo[i]; sh += hi[i+7] - hi[i]; }
            }
        }
        float* op = out + (size_t)b * HW + (size_t)(y0 + 4*rb) * W + (x0 + 2*cp);
#pragma unroll
        for (int i = 0; i < 4; ++i) {
            f32x2 r2;
            r2.x = (49.0f - Dlo[i]) * 0.125f;
            r2.y = (49.0f - Dhi[i]) * 0.125f;
            *(f32x2*)(op + (size_t)i * W) = r2;     // lanes 0..31 contiguous 256B
        }
    }
}

extern "C" void kernel_launch(void* const* d_in, const int* in_sizes, int n_in,
                              void* d_out, int out_size, void* d_ws, size_t ws_size,
                              hipStream_t stream) {
    (void)n_in; (void)d_ws; (void)ws_size; (void)out_size;
    const float* x = (const float*)d_in[0];
    float* out = (float*)d_out;

    const int H = 512, W = 512, C = 3;
    const int B = in_sizes[0] / (C * H * W);        // 32

    const int tilesPerImg = (W / TW) * (H / TH);    // 128
    mcnd_kernel<<<B * tilesPerImg, 256, 0, stream>>>(x, out, B, H, W);
}